// Round 11
// baseline (503.902 us; speedup 1.0000x reference)
//
#include <hip/hip_runtime.h>
#include <hip/hip_bf16.h>
#include <math.h>
#include <stdint.h>

typedef __hip_bfloat16 bf16;
using f32x4 = __attribute__((ext_vector_type(4))) float;
using s16x8 = __attribute__((ext_vector_type(8))) short;

constexpr int Bc = 2, Sc = 2048, Hc = 2048, NHc = 32, HDc = 64;
constexpr int Mc = Bc * Sc;      // 4096 rows
constexpr int MAXPOS = 8192;

// ---------------- workspace layout (bytes) ----------------
constexpr size_t OFF_WV  = 0;
constexpr size_t OFF_WQK = OFF_WV  + (size_t)Hc * Hc * 2;
constexpr size_t OFF_WO  = OFF_WQK + (size_t)2 * Hc * Hc * 2;
constexpr size_t OFF_W1  = OFF_WO  + (size_t)Hc * Hc * 2;
constexpr size_t OFF_W2  = OFF_W1  + (size_t)(Hc/2) * (2*Hc) * 2;
constexpr size_t OFF_HS  = OFF_W2  + (size_t)Hc * Hc * 2;
constexpr size_t OFF_XPR = OFF_HS  + (size_t)Mc * Hc * 2;
constexpr size_t OFF_O1  = OFF_XPR + (size_t)Mc * Hc * 2;
constexpr size_t OFF_O1P = OFF_O1  + (size_t)Mc * (Hc/2) * 2;
constexpr size_t OFF_O2  = OFF_O1P + (size_t)Mc * (Hc/2) * 2;
constexpr size_t OFF_LF  = OFF_O2  + (size_t)Mc * Hc * 4;
constexpr size_t OFF_VT  = OFF_LF  + (size_t)Mc * Hc * 2;
constexpr size_t OFF_COS = OFF_VT  + (size_t)Mc * Hc * 2;
constexpr size_t OFF_SIN = OFF_COS + (size_t)MAXPOS * HDc * 4;
constexpr size_t OFF_Q   = OFF_XPR;  // q over xprev
constexpr size_t OFF_K   = OFF_HS;   // k over hs
constexpr size_t OFF_CTX = OFF_O1;   // ctx over o1+o1prev

// ---------------- helpers ----------------
__device__ __forceinline__ f32x4 mfma16(s16x8 a, s16x8 b, f32x4 c) {
  return __builtin_amdgcn_mfma_f32_16x16x32_bf16(a, b, c, 0, 0, 0);
}
__device__ __forceinline__ void gload16(const bf16* g, bf16* l) {
  __builtin_amdgcn_global_load_lds(
      (__attribute__((address_space(1))) void*)g,
      (__attribute__((address_space(3))) void*)l, 16, 0, 0);
}
__device__ __forceinline__ uint16_t bfbits(float x) {
  union { bf16 h; uint16_t u; } v; v.h = __float2bfloat16(x); return v.u;
}
__device__ __forceinline__ uint32_t pkbf(float a, float b) {
  return (uint32_t)bfbits(a) | ((uint32_t)bfbits(b) << 16);
}
__device__ __forceinline__ void block_bar() {
  asm volatile("" ::: "memory");
  __builtin_amdgcn_s_barrier();
  asm volatile("" ::: "memory");
}
template <int N> __device__ __forceinline__ void vm_wait() {
  if constexpr (N == 0)      asm volatile("s_waitcnt vmcnt(0)" ::: "memory");
  else if constexpr (N == 3) asm volatile("s_waitcnt vmcnt(3)" ::: "memory");
  else if constexpr (N == 4) asm volatile("s_waitcnt vmcnt(4)" ::: "memory");
  else if constexpr (N == 6) asm volatile("s_waitcnt vmcnt(6)" ::: "memory");
  else if constexpr (N == 8) asm volatile("s_waitcnt vmcnt(8)" ::: "memory");
}

// ---------------- small conversion kernels ----------------
__global__ void k_cvt(const float* __restrict__ in, bf16* __restrict__ out, int n) {
  int i = blockIdx.x * 256 + threadIdx.x;
  if (i < n) out[i] = __float2bfloat16(in[i]);
}

__global__ void k_cvt_hs(const float* __restrict__ hs, const float* __restrict__ lf1,
                         bf16* __restrict__ hsb, bf16* __restrict__ xprev) {
  int i = blockIdx.x * 256 + threadIdx.x;      // over M*H
  if (i >= Mc * Hc) return;
  float v = hs[i];
  bf16 b = __float2bfloat16(v);
  hsb[i] = b;
  int row = i >> 11, col = i & (Hc - 1);
  int s = row & (Sc - 1), bb = row >> 11;
  if (s + 1 < Sc) xprev[i + Hc] = b;
  if (s == 0)     xprev[i] = __float2bfloat16(lf1[bb * Hc + col]);
}

__global__ void k_repack1(const float* __restrict__ w, bf16* __restrict__ out) {
  int i = blockIdx.x * 256 + threadIdx.x;      // 1024*4096
  if (i >= (Hc/2) * 2 * Hc) return;
  int oc = i >> 12, k = i & 4095;
  int ic = k & (Hc - 1), t = k >> 11;
  out[i] = __float2bfloat16(w[((size_t)oc * Hc + ic) * 2 + t]);
}
__global__ void k_repack2(const float* __restrict__ w, bf16* __restrict__ out) {
  int i = blockIdx.x * 256 + threadIdx.x;      // 2048*2048
  if (i >= Hc * Hc) return;
  int c = i >> 11, k = i & (Hc - 1);
  int oc = k & (Hc/2 - 1), t = k >> 10;
  out[i] = __float2bfloat16(w[((size_t)c * (Hc/2) + oc) * 2 + t]);
}

__global__ void k_prefill_o1p(const float* __restrict__ lf2, bf16* __restrict__ o1p) {
  int i = blockIdx.x * 256 + threadIdx.x;      // B * H/2
  if (i >= Bc * (Hc/2)) return;
  int b = i >> 10, n = i & (Hc/2 - 1);
  o1p[(size_t)b * Sc * (Hc/2) + n] = __float2bfloat16(lf2[i]);
}

struct InvF { double v[32]; double mscale; };

__global__ void k_costab(InvF f, float* __restrict__ ct, float* __restrict__ st) {
  int i = blockIdx.x * 256 + threadIdx.x;      // MAXPOS*64
  if (i >= MAXPOS * HDc) return;
  int p = i >> 6, d = i & 63;
  double ang = (double)p * f.v[d & 31];
  ct[i] = (float)(cos(ang) * f.mscale);
  st[i] = (float)(sin(ang) * f.mscale);
}

// ---------------- RMSNorm (block per row) ----------------
__global__ __launch_bounds__(256) void k_rmsnorm(const float* __restrict__ x,
                                                 const float* __restrict__ w,
                                                 bf16* __restrict__ out) {
  __shared__ float red[4];
  int row = blockIdx.x;
  const float* xr = x + (size_t)row * Hc;
  float ss = 0.f;
  for (int c = threadIdx.x; c < Hc; c += 256) { float v = xr[c]; ss += v * v; }
  for (int off = 32; off; off >>= 1) ss += __shfl_down(ss, off, 64);
  if ((threadIdx.x & 63) == 0) red[threadIdx.x >> 6] = ss;
  __syncthreads();
  float sc = rsqrtf((red[0] + red[1] + red[2] + red[3]) / Hc + 1e-6f);
  for (int c = threadIdx.x; c < Hc; c += 256)
    out[(size_t)row * Hc + c] = __float2bfloat16(xr[c] * sc * w[c]);
}

// ---------------- 2-phase GEMM (conv1 only), default block mapping --------
template <int EPI, int BM = 128>
__global__ __launch_bounds__(256) void gemm_bt(
    const bf16* __restrict__ A0, const bf16* __restrict__ A1, int Ksplit,
    const bf16* __restrict__ Bw, int K, int N, void* __restrict__ Cout,
    const float* __restrict__ bias, const float* __restrict__ resid,
    bf16* __restrict__ aux) {
  constexpr int MR = BM / 32;
  __shared__ __align__(16) bf16 As[2][BM * 32];
  __shared__ __align__(16) bf16 Bs[2][128 * 32];
  const int tid = threadIdx.x;
  const int bm = blockIdx.y, bn = blockIdx.x;
  const int w = tid >> 6, l = tid & 63;
  const int wm = (w >> 1) * (BM / 2), wn = (w & 1) * 64;
  const int lrow = l & 15, lg = l >> 4, lk = lg * 8;
  const int r0 = tid >> 2, cofs = (tid & 3) * 8;

  auto stage = [&](int buf, int kt) {
    const int kcol = kt * 32;
    const bf16* Au; int kc;
    if (kcol < Ksplit) { Au = A0; kc = kcol; } else { Au = A1; kc = kcol - Ksplit; }
    gload16(Au + (size_t)(bm * BM + r0) * Ksplit + kc + cofs,        &As[buf][tid * 8]);
    if constexpr (BM == 128)
      gload16(Au + (size_t)(bm * BM + r0 + 64) * Ksplit + kc + cofs, &As[buf][2048 + tid * 8]);
    gload16(Bw + (size_t)(bn * 128 + r0) * K + kcol + cofs,          &Bs[buf][tid * 8]);
    gload16(Bw + (size_t)(bn * 128 + r0 + 64) * K + kcol + cofs,     &Bs[buf][2048 + tid * 8]);
  };

  f32x4 acc[MR][4] = {};
  const int nkt = K / 32;
  stage(0, 0);
  __syncthreads();
  for (int kt = 0; kt < nkt; ++kt) {
    const int cur = kt & 1;
    if (kt + 1 < nkt) stage(cur ^ 1, kt + 1);
    s16x8 af[MR], bfr[4];
#pragma unroll
    for (int m = 0; m < MR; ++m)
      af[m] = *(const s16x8*)&As[cur][(wm + m * 16 + lrow) * 32 + lk];
#pragma unroll
    for (int n = 0; n < 4; ++n)
      bfr[n] = *(const s16x8*)&Bs[cur][(wn + n * 16 + lrow) * 32 + lk];
    __builtin_amdgcn_s_setprio(1);
#pragma unroll
    for (int m = 0; m < MR; ++m)
#pragma unroll
      for (int n = 0; n < 4; ++n)
        acc[m][n] = mfma16(af[m], bfr[n], acc[m][n]);
    __builtin_amdgcn_s_setprio(0);
    __syncthreads();
  }
#pragma unroll
  for (int m = 0; m < MR; ++m)
#pragma unroll
    for (int n = 0; n < 4; ++n)
#pragma unroll
      for (int r = 0; r < 4; ++r) {
        const int grow = bm * BM + wm + m * 16 + lg * 4 + r;
        const int gcol = bn * 128 + wn + n * 16 + lrow;
        float v = acc[m][n][r];
        if constexpr (EPI == 1) {
          v += bias[gcol];
          bf16 bv = __float2bfloat16(v);
          ((bf16*)Cout)[(size_t)grow * N + gcol] = bv;
          if ((grow & (Sc - 1)) != Sc - 1) aux[(size_t)(grow + 1) * N + gcol] = bv;
        } else {
          ((float*)Cout)[(size_t)grow * N + gcol] = v;
        }
      }
}

// ---------------- 256-wide triple-buffered counted-vmcnt GEMM -------------
// EPI: 2 +bias+resid fp32 | 4 fp32 | 5 v^T store | 6 fused-RoPE q/k writer
template <int EPI, int BN>
__global__ __launch_bounds__(512, 2) void gemm8(
    const bf16* __restrict__ A0, const bf16* __restrict__ A1, int Ksplit,
    const bf16* __restrict__ Bw, int K, int N, void* __restrict__ Cout,
    const float* __restrict__ bias, const float* __restrict__ resid,
    const int* __restrict__ pos, const float* __restrict__ ct,
    const float* __restrict__ st, bf16* __restrict__ out2) {
  constexpr int BM = 256;
  constexpr int L = (BN == 256) ? 4 : 3;        // gload16 per thread per tile
  constexpr int TILE = (BM + BN) * 32;
  constexpr int MR = (BN == 256) ? 8 : 4;
  __shared__ __align__(16) bf16 lds[3][TILE];
  const int tid = threadIdx.x;
  const int w = tid >> 6, l = tid & 63;
  const int lrow = l & 15, lg = l >> 4;
  const int wm = (BN == 256) ? (w >> 2) * 128 : (w & 3) * 64;
  const int wn = (BN == 256) ? (w & 3) * 64 : (w >> 2) * 64;
  // rect XCD swizzle: XCD c gets a (gx/4)x(gy/2) block rectangle
  const int gx = gridDim.x;
  const int lin = blockIdx.y * gx + blockIdx.x;
  const int cx = gx >> 2, cy = gridDim.y >> 1;
  const int c = lin & 7, idx = lin >> 3;
  const int bn = (c & 3) * cx + idx % cx;
  const int bm = (c >> 2) * cy + idx / cx;

  auto ld1 = [&](const bf16* srcbase, size_t stride, bf16* ldst, int ci) {
    const int pr = ci >> 3, rem = ci & 7;
    const int r = pr * 2 + (rem >> 2), g = (rem & 3) ^ (pr & 3);
    gload16(srcbase + (size_t)r * stride + g * 8, ldst + ci * 8);
  };
  auto stage = [&](int kt, int slot) {
    const int kcol = kt * 32;
    const bf16* Au; int kc;
    if (kcol < Ksplit) { Au = A0; kc = kcol; } else { Au = A1; kc = kcol - Ksplit; }
    const bf16* As_ = Au + (size_t)bm * BM * Ksplit + kc;
    bf16* ldsA = lds[slot];
    ld1(As_, Ksplit, ldsA, tid);
    ld1(As_, Ksplit, ldsA, tid + 512);
    const bf16* Bs_ = Bw + (size_t)bn * BN * K + kcol;
    bf16* ldsB = lds[slot] + BM * 32;
    ld1(Bs_, K, ldsB, tid);
    if constexpr (BN == 256) ld1(Bs_, K, ldsB, tid + 512);
  };
  auto frag = [&](const bf16* base, int r) -> s16x8 {
    const int s = ((r >> 1) << 3) + ((r & 1) << 2) + (lg ^ ((r >> 1) & 3));
    return *(const s16x8*)(base + s * 8);
  };

  f32x4 acc[MR][4] = {};
  const int nkt = K / 32;
  stage(0, 0);
  stage(1, 1);
  for (int t = 0; t < nkt; ++t) {
    if (t + 2 < nkt) { stage(t + 2, (t + 2) % 3); vm_wait<2 * L>(); }
    else if (t + 1 < nkt) { vm_wait<L>(); }
    else { vm_wait<0>(); }
    block_bar();
    const bf16* Asl = lds[t % 3];
    const bf16* Bsl = Asl + BM * 32;
    s16x8 af[MR], bfr[4];
#pragma unroll
    for (int m = 0; m < MR; ++m) af[m] = frag(Asl, wm + m * 16 + lrow);
#pragma unroll
    for (int n = 0; n < 4; ++n) bfr[n] = frag(Bsl, wn + n * 16 + lrow);
    __builtin_amdgcn_s_setprio(1);
#pragma unroll
    for (int m = 0; m < MR; ++m)
#pragma unroll
      for (int n = 0; n < 4; ++n)
        acc[m][n] = mfma16(af[m], bfr[n], acc[m][n]);
    __builtin_amdgcn_s_setprio(0);
    block_bar();
  }
  if constexpr (EPI == 6) {
    // fused RoPE: wave's 64-col window = one (head, q|k) half. Pairs are
    // acc[m][n] (d) / acc[m][n+2] (d+32), n in {0,1}.
    const int gcol0 = bn * BN + wn;            // wave-uniform
    const int h = gcol0 >> 7, half = (gcol0 >> 6) & 1;
    bf16* outp = half ? out2 : (bf16*)Cout;
    const float qsc = half ? 1.0f : 0.125f * 1.44269504088896f;
#pragma unroll
    for (int m = 0; m < MR; ++m)
#pragma unroll
      for (int r = 0; r < 4; ++r) {
        const int grow = bm * BM + wm + m * 16 + lg * 4 + r;
        const int p = pos[grow];
        const int bb = grow >> 11, s = grow & (Sc - 1);
        bf16* rowp = outp + ((size_t)(bb * NHc + h) * Sc + s) * 64;
#pragma unroll
        for (int n = 0; n < 2; ++n) {
          const int dd = n * 16 + lrow;
          const float c0 = ct[p * 64 + dd],      s0 = st[p * 64 + dd];
          const float c1 = ct[p * 64 + 32 + dd], s1 = st[p * 64 + 32 + dd];
          const float v0 = acc[m][n][r], v1 = acc[m][n + 2][r];
          rowp[dd]      = __float2bfloat16((v0 * c0 - v1 * s0) * qsc);
          rowp[dd + 32] = __float2bfloat16((v1 * c1 + v0 * s1) * qsc);
        }
      }
  } else {
#pragma unroll
    for (int m = 0; m < MR; ++m)
#pragma unroll
      for (int n = 0; n < 4; ++n)
#pragma unroll
        for (int r = 0; r < 4; ++r) {
          const int grow = bm * BM + wm + m * 16 + lg * 4 + r;
          const int gcol = bn * BN + wn + n * 16 + lrow;
          float v = acc[m][n][r];
          if constexpr (EPI == 2) {
            v += bias[gcol] + resid[(size_t)grow * N + gcol];
            ((float*)Cout)[(size_t)grow * N + gcol] = v;
          } else if constexpr (EPI == 5) {
            const int b = gcol >> 11, s = gcol & (Sc - 1);
            ((bf16*)Cout)[((size_t)(b * Hc + grow)) * Sc + s] = __float2bfloat16(v);
          } else {
            ((float*)Cout)[(size_t)grow * N + gcol] = v;
          }
        }
  }
}

// ---------------- causal flash attention (3-slot counted-vmcnt staging) ---
// Q (pre-scaled, exp2 domain), K: (b,h,s,d) bf16; Vt: (b,h,d,s) bf16;
// ctx: (b,s,h*64+d) bf16. gemm8 protocol: stage t+2, vmcnt(8), raw barrier,
// compute slot t%3, barrier. Q-frag loads precede staging -> oldest-first
// ordering keeps the counted waits conservative. Pass-end vmcnt(0) drains
// the ctx stores before the next pass's staging counts.
__global__ __launch_bounds__(256) void k_attn(const bf16* __restrict__ Q,
                                              const bf16* __restrict__ Kg,
                                              const bf16* __restrict__ Vt,
                                              bf16* __restrict__ ctx) {
  __shared__ __align__(16) bf16 Ks[3][64 * 64];
  __shared__ __align__(16) bf16 Vs[3][64 * 64];
  __shared__ __align__(16) uint32_t Pl[4][2][2][16][20];
  const int tid = threadIdx.x;
  const int w = tid >> 6, l = tid & 63;
  const int lrow = l & 15, lg = l >> 4, lk = lg * 8;
  const int bh = blockIdx.x;
  const int tile = blockIdx.y;
  const bf16* Qp = Q  + (size_t)bh * Sc * HDc;
  const bf16* Kp = Kg + (size_t)bh * Sc * HDc;
  const bf16* Vp = Vt + (size_t)bh * HDc * Sc;
  const int b = bh >> 5, h = bh & 31;
  const s16x8 ones8 = {16256, 16256, 16256, 16256, 16256, 16256, 16256, 16256};

  const int srow0 = tid >> 3, schunk = tid & 7;

  auto stage = [&](int kv0, int slot) {
    gload16(Kp + (size_t)(kv0 + srow0) * 64 + ((schunk ^ (srow0 & 7)) << 3),
            &Ks[slot][tid * 8]);
    gload16(Kp + (size_t)(kv0 + 32 + srow0) * 64 + ((schunk ^ ((32 + srow0) & 7)) << 3),
            &Ks[slot][2048 + tid * 8]);
    gload16(Vp + (size_t)srow0 * Sc + kv0 + ((schunk ^ (srow0 & 7)) << 3),
            &Vs[slot][tid * 8]);
    gload16(Vp + (size_t)(32 + srow0) * Sc + kv0 + ((schunk ^ ((32 + srow0) & 7)) << 3),
            &Vs[slot][2048 + tid * 8]);
  };

  for (int pass = 0; pass < 2; ++pass) {
    const int base = (pass == 0) ? tile * 128 : (Sc - 128 - tile * 128);
    const int q0 = base + w * 32;
    const int NT = base / 64 + 2;      // >= 2, block-uniform

    s16x8 qa[2][2];
#pragma unroll
    for (int m = 0; m < 2; ++m)
#pragma unroll
      for (int hf = 0; hf < 2; ++hf)
        qa[m][hf] = *(const s16x8*)&Qp[(size_t)(q0 + m * 16 + lrow) * 64 + hf * 32 + lk];

    f32x4 o[2][4] = {};
    f32x4 lsf[2] = {};
    float mx[2] = {-1e30f, -1e30f};

    stage(0, 0);
    stage(64, 1);

    for (int t = 0; t < NT; ++t) {
      const int kv0 = t * 64;
      if (t + 2 < NT)      { stage(kv0 + 128, (t + 2) % 3); vm_wait<8>(); }
      else if (t + 1 < NT) { vm_wait<4>(); }
      else                 { vm_wait<0>(); }
      block_bar();                     // tile t landed in all waves
      if (kv0 <= q0) {
        const bf16* Kc = Ks[t % 3];
        const bf16* Vc = Vs[t % 3];
        s16x8 kc[8], vc[4][2];
#pragma unroll
        for (int c = 0; c < 4; ++c)
#pragma unroll
          for (int hf = 0; hf < 2; ++hf) {
            const int row = c * 16 + lrow;
            kc[c * 2 + hf] =
                *(const s16x8*)&Kc[row * 64 + (((hf << 2) + lg) ^ (row & 7)) * 8];
          }
#pragma unroll
        for (int db = 0; db < 4; ++db)
#pragma unroll
          for (int kh = 0; kh < 2; ++kh) {
            const int row = db * 16 + lrow;
            vc[db][kh] =
                *(const s16x8*)&Vc[row * 64 + (((kh << 2) + lg) ^ (row & 7)) * 8];
          }
        const bool lastit = (kv0 + 64 > q0);

#pragma unroll
        for (int m = 0; m < 2; ++m) {
          f32x4 s[4];
          __builtin_amdgcn_s_setprio(1);
#pragma unroll
          for (int c = 0; c < 4; ++c) {
            f32x4 z = {};
            z = mfma16(kc[c * 2], qa[m][0], z);
            z = mfma16(kc[c * 2 + 1], qa[m][1], z);
            s[c] = z;
          }
          __builtin_amdgcn_s_setprio(0);

          if (lastit) {
            const int qq = q0 + m * 16 + lrow;
#pragma unroll
            for (int c = 0; c < 4; ++c)
#pragma unroll
              for (int r = 0; r < 4; ++r)
                if (kv0 + c * 16 + lg * 4 + r > qq) s[c][r] = -1e30f;
          }
          float t16 = fmaxf(
              fmaxf(fmaxf(fmaxf(s[0][0], s[0][1]), fmaxf(s[0][2], s[0][3])),
                    fmaxf(fmaxf(s[1][0], s[1][1]), fmaxf(s[1][2], s[1][3]))),
              fmaxf(fmaxf(fmaxf(s[2][0], s[2][1]), fmaxf(s[2][2], s[2][3])),
                    fmaxf(fmaxf(s[3][0], s[3][1]), fmaxf(s[3][2], s[3][3]))));
          if (!__all(t16 <= mx[m] + 8.0f)) {
            t16 = fmaxf(t16, __shfl_xor(t16, 16, 64));
            t16 = fmaxf(t16, __shfl_xor(t16, 32, 64));
            const float mnew = fmaxf(mx[m], t16);
            const float sold = __builtin_amdgcn_exp2f(mx[m] - mnew);
            mx[m] = mnew;
            lsf[m] *= sold;
#pragma unroll
            for (int db = 0; db < 4; ++db) o[m][db] *= sold;
          }
          float p[4][4];
#pragma unroll
          for (int c = 0; c < 4; ++c)
#pragma unroll
            for (int r = 0; r < 4; ++r)
              p[c][r] = __builtin_amdgcn_exp2f(s[c][r] - mx[m]);
#pragma unroll
          for (int kh = 0; kh < 2; ++kh) {
            *(uint64_t*)&Pl[w][m][kh][lrow][lg * 2] =
                (uint64_t)pkbf(p[kh * 2][0], p[kh * 2][1]) |
                ((uint64_t)pkbf(p[kh * 2][2], p[kh * 2][3]) << 32);
            *(uint64_t*)&Pl[w][m][kh][lrow][8 + lg * 2] =
                (uint64_t)pkbf(p[kh * 2 + 1][0], p[kh * 2 + 1][1]) |
                ((uint64_t)pkbf(p[kh * 2 + 1][2], p[kh * 2 + 1][3]) << 32);
          }
          const s16x8 pb0 = *(const s16x8*)&Pl[w][m][0][lrow][lg * 4];
          const s16x8 pb1 = *(const s16x8*)&Pl[w][m][1][lrow][lg * 4];
          __builtin_amdgcn_s_setprio(1);
#pragma unroll
          for (int db = 0; db < 4; ++db) o[m][db] = mfma16(vc[db][0], pb0, o[m][db]);
          lsf[m] = mfma16(ones8, pb0, lsf[m]);
#pragma unroll
          for (int db = 0; db < 4; ++db) o[m][db] = mfma16(vc[db][1], pb1, o[m][db]);
          lsf[m] = mfma16(ones8, pb1, lsf[m]);
          __builtin_amdgcn_s_setprio(0);
        }
      }
      block_bar();                     // slot reads done before re-stage
    }
#pragma unroll
    for (int m = 0; m < 2; ++m) {
      const float inv = 1.0f / lsf[m][0];
      const int qrow = q0 + m * 16 + lrow;
      const size_t rowoff = ((size_t)(b * Sc + qrow)) * Hc + h * 64;
#pragma unroll
      for (int db = 0; db < 4; ++db) {
        uint64_t pk = (uint64_t)bfbits(o[m][db][0] * inv) |
                      ((uint64_t)bfbits(o[m][db][1] * inv) << 16) |
                      ((uint64_t)bfbits(o[m][db][2] * inv) << 32) |
                      ((uint64_t)bfbits(o[m][db][3] * inv) << 48);
        *(uint64_t*)&ctx[rowoff + db * 16 + lg * 4] = pk;
      }
    }
    vm_wait<0>();                      // drain ctx stores: keeps pass-1 counts exact
    block_bar();
  }
}

// ---------------- host ----------------
extern "C" void kernel_launch(void* const* d_in, const int* in_sizes, int n_in,
                              void* d_out, int out_size, void* d_ws, size_t ws_size,
                              hipStream_t stream) {
  (void)in_sizes; (void)n_in; (void)out_size; (void)ws_size;
  const float* hs  = (const float*)d_in[0];
  const int*   pos = (const int*)d_in[1];
  const float* lf1 = (const float*)d_in[2];
  const float* lf2 = (const float*)d_in[3];
  const float* Wqk = (const float*)d_in[4];
  const float* Wv  = (const float*)d_in[5];
  const float* Wo  = (const float*)d_in[6];
  const float* c1w = (const float*)d_in[7];
  const float* c1b = (const float*)d_in[8];
  const float* c2w = (const float*)d_in[9];
  const float* c2b = (const float*)d_in[10];
  const float* lnw = (const float*)d_in[11];
  float* out = (float*)d_out;
  char*  ws  = (char*)d_ws;

  bf16* wvB   = (bf16*)(ws + OFF_WV);
  bf16* wqkB  = (bf16*)(ws + OFF_WQK);
  bf16* woB   = (bf16*)(ws + OFF_WO);
  bf16* w1B   = (bf16*)(ws + OFF_W1);
  bf16* w2B   = (bf16*)(ws + OFF_W2);
  bf16* hsB   = (bf16*)(ws + OFF_HS);
  bf16* xprB  = (bf16*)(ws + OFF_XPR);
  bf16* o1B   = (bf16*)(ws + OFF_O1);
  bf16* o1pB  = (bf16*)(ws + OFF_O1P);
  float* o2F  = (float*)(ws + OFF_O2);
  bf16* lfB   = (bf16*)(ws + OFF_LF);
  bf16* vtB   = (bf16*)(ws + OFF_VT);
  float* cosT = (float*)(ws + OFF_COS);
  float* sinT = (float*)(ws + OFF_SIN);
  bf16* qB    = (bf16*)(ws + OFF_Q);
  bf16* kB    = (bf16*)(ws + OFF_K);
  bf16* ctxB  = (bf16*)(ws + OFF_CTX);

  // YaRN inv_freq on host (fp64), matching the reference exactly
  InvF f;
  {
    const double base = 10000.0, scale = 2.0;
    const int hd = HDc;
    auto corr = [&](double nr) {
      return hd * log(8192.0 / (nr * 2.0 * M_PI)) / (2.0 * log(base));
    };
    double low = floor(corr(32.0)); if (low < 0) low = 0;
    double high = ceil(corr(1.0));  if (high > hd - 1) high = hd - 1;
    double hi = (low == high) ? high + 0.001 : high;
    for (int i = 0; i < 32; ++i) {
      double inv = 1.0 / pow(base, (2.0 * i) / hd);
      double ramp = ((double)i - low) / (hi - low);
      ramp = ramp < 0.0 ? 0.0 : (ramp > 1.0 ? 1.0 : ramp);
      double mask = 1.0 - ramp;
      f.v[i] = inv / ((1.0 - mask) * scale + mask);
    }
    f.mscale = 0.1 * log(scale) + 1.0;
  }

  // conversions / repacks / tables
  k_cvt<<<(Hc * Hc + 255) / 256, 256, 0, stream>>>(Wv, wvB, Hc * Hc);
  k_cvt<<<(2 * Hc * Hc + 255) / 256, 256, 0, stream>>>(Wqk, wqkB, 2 * Hc * Hc);
  k_cvt<<<(Hc * Hc + 255) / 256, 256, 0, stream>>>(Wo, woB, Hc * Hc);
  k_repack1<<<((Hc / 2) * 2 * Hc + 255) / 256, 256, 0, stream>>>(c1w, w1B);
  k_repack2<<<(Hc * Hc + 255) / 256, 256, 0, stream>>>(c2w, w2B);
  k_cvt_hs<<<(Mc * Hc + 255) / 256, 256, 0, stream>>>(hs, lf1, hsB, xprB);
  k_prefill_o1p<<<(Bc * (Hc / 2) + 255) / 256, 256, 0, stream>>>(lf2, o1pB);
  k_costab<<<(MAXPOS * HDc + 255) / 256, 256, 0, stream>>>(f, cosT, sinT);

  // conv1: o1 = [xprev|x] @ w1cat^T + b1  (2-phase, BM=64)
  gemm_bt<1, 64><<<dim3((Hc / 2) / 128, Mc / 64), 256, 0, stream>>>(
      xprB, hsB, Hc, w1B, 2 * Hc, Hc / 2, o1B, c1b, nullptr, o1pB);
  // v^T: C'[hd][(b,s)] = Wv @ hs^T
  gemm8<5, 128><<<dim3(Mc / 128, Hc / 256), 512, 0, stream>>>(
      wvB, wvB, Hc, hsB, Hc, Mc, vtB, nullptr, nullptr, nullptr, nullptr, nullptr, nullptr);
  // conv2: o2res = [o1prev|o1] @ w2cat^T + b2 + hidden  (fp32)
  gemm8<2, 128><<<dim3(Hc / 128, Mc / 256), 512, 0, stream>>>(
      o1pB, o1B, Hc / 2, w2B, Hc, Hc, o2F, c2b, hs, nullptr, nullptr, nullptr, nullptr);
  // lf = rmsnorm(o2res) * ln_w
  k_rmsnorm<<<Mc, 256, 0, stream>>>(o2F, lnw, lfB);
  // qk = lf @ Wqk^T with fused RoPE -> q (pre-scaled, exp2 domain), k
  gemm8<6, 256><<<dim3((2 * Hc) / 256, Mc / 256), 512, 0, stream>>>(
      lfB, lfB, Hc, wqkB, Hc, 2 * Hc, qB, nullptr, nullptr, pos, cosT, sinT, kB);
  // causal flash attention -> ctx (b,s,h*64+d)
  k_attn<<<dim3(64, 8), 256, 0, stream>>>(qB, kB, vtB, ctxB);
  // out = ctx @ Wo^T  (fp32)
  gemm8<4, 128><<<dim3(Hc / 128, Mc / 256), 512, 0, stream>>>(
      ctxB, ctxB, Hc, woB, Hc, Hc, out, nullptr, nullptr, nullptr, nullptr, nullptr, nullptr);
}

// Round 12
// 461.618 us; speedup vs baseline: 1.0916x; 1.0916x over previous
//
#include <hip/hip_runtime.h>
#include <hip/hip_bf16.h>
#include <math.h>
#include <stdint.h>

typedef __hip_bfloat16 bf16;
using f32x4 = __attribute__((ext_vector_type(4))) float;
using s16x8 = __attribute__((ext_vector_type(8))) short;

constexpr int Bc = 2, Sc = 2048, Hc = 2048, NHc = 32, HDc = 64;
constexpr int Mc = Bc * Sc;      // 4096 rows
constexpr int MAXPOS = 8192;

// ---------------- workspace layout (bytes) ----------------
constexpr size_t OFF_WV  = 0;
constexpr size_t OFF_WQK = OFF_WV  + (size_t)Hc * Hc * 2;
constexpr size_t OFF_WO  = OFF_WQK + (size_t)2 * Hc * Hc * 2;
constexpr size_t OFF_W1  = OFF_WO  + (size_t)Hc * Hc * 2;
constexpr size_t OFF_W2  = OFF_W1  + (size_t)(Hc/2) * (2*Hc) * 2;
constexpr size_t OFF_HS  = OFF_W2  + (size_t)Hc * Hc * 2;
constexpr size_t OFF_XPR = OFF_HS  + (size_t)Mc * Hc * 2;
constexpr size_t OFF_O1  = OFF_XPR + (size_t)Mc * Hc * 2;
constexpr size_t OFF_O1P = OFF_O1  + (size_t)Mc * (Hc/2) * 2;
constexpr size_t OFF_O2  = OFF_O1P + (size_t)Mc * (Hc/2) * 2;
constexpr size_t OFF_LF  = OFF_O2  + (size_t)Mc * Hc * 4;
constexpr size_t OFF_VT  = OFF_LF  + (size_t)Mc * Hc * 2;
constexpr size_t OFF_COS = OFF_VT  + (size_t)Mc * Hc * 2;
constexpr size_t OFF_SIN = OFF_COS + (size_t)MAXPOS * HDc * 4;
constexpr size_t OFF_Q   = OFF_XPR;  // q over xprev
constexpr size_t OFF_K   = OFF_HS;   // k over hs
constexpr size_t OFF_CTX = OFF_O1;   // ctx over o1+o1prev

// ---------------- helpers ----------------
__device__ __forceinline__ f32x4 mfma16(s16x8 a, s16x8 b, f32x4 c) {
  return __builtin_amdgcn_mfma_f32_16x16x32_bf16(a, b, c, 0, 0, 0);
}
__device__ __forceinline__ void gload16(const bf16* g, bf16* l) {
  __builtin_amdgcn_global_load_lds(
      (__attribute__((address_space(1))) void*)g,
      (__attribute__((address_space(3))) void*)l, 16, 0, 0);
}
__device__ __forceinline__ uint16_t bfbits(float x) {
  union { bf16 h; uint16_t u; } v; v.h = __float2bfloat16(x); return v.u;
}
__device__ __forceinline__ uint32_t pkbf(float a, float b) {
  return (uint32_t)bfbits(a) | ((uint32_t)bfbits(b) << 16);
}
__device__ __forceinline__ void block_bar() {
  asm volatile("" ::: "memory");
  __builtin_amdgcn_s_barrier();
  asm volatile("" ::: "memory");
}
template <int N> __device__ __forceinline__ void vm_wait() {
  if constexpr (N == 0)      asm volatile("s_waitcnt vmcnt(0)" ::: "memory");
  else if constexpr (N == 3) asm volatile("s_waitcnt vmcnt(3)" ::: "memory");
  else if constexpr (N == 4) asm volatile("s_waitcnt vmcnt(4)" ::: "memory");
  else if constexpr (N == 6) asm volatile("s_waitcnt vmcnt(6)" ::: "memory");
  else if constexpr (N == 8) asm volatile("s_waitcnt vmcnt(8)" ::: "memory");
}

// ---------------- small conversion kernels ----------------
__global__ void k_cvt(const float* __restrict__ in, bf16* __restrict__ out, int n) {
  int i = blockIdx.x * 256 + threadIdx.x;
  if (i < n) out[i] = __float2bfloat16(in[i]);
}

__global__ void k_cvt_hs(const float* __restrict__ hs, const float* __restrict__ lf1,
                         bf16* __restrict__ hsb, bf16* __restrict__ xprev) {
  int i = blockIdx.x * 256 + threadIdx.x;      // over M*H
  if (i >= Mc * Hc) return;
  float v = hs[i];
  bf16 b = __float2bfloat16(v);
  hsb[i] = b;
  int row = i >> 11, col = i & (Hc - 1);
  int s = row & (Sc - 1), bb = row >> 11;
  if (s + 1 < Sc) xprev[i + Hc] = b;
  if (s == 0)     xprev[i] = __float2bfloat16(lf1[bb * Hc + col]);
}

__global__ void k_repack1(const float* __restrict__ w, bf16* __restrict__ out) {
  int i = blockIdx.x * 256 + threadIdx.x;      // 1024*4096
  if (i >= (Hc/2) * 2 * Hc) return;
  int oc = i >> 12, k = i & 4095;
  int ic = k & (Hc - 1), t = k >> 11;
  out[i] = __float2bfloat16(w[((size_t)oc * Hc + ic) * 2 + t]);
}
__global__ void k_repack2(const float* __restrict__ w, bf16* __restrict__ out) {
  int i = blockIdx.x * 256 + threadIdx.x;      // 2048*2048
  if (i >= Hc * Hc) return;
  int c = i >> 11, k = i & (Hc - 1);
  int oc = k & (Hc/2 - 1), t = k >> 10;
  out[i] = __float2bfloat16(w[((size_t)c * (Hc/2) + oc) * 2 + t]);
}

__global__ void k_prefill_o1p(const float* __restrict__ lf2, bf16* __restrict__ o1p) {
  int i = blockIdx.x * 256 + threadIdx.x;      // B * H/2
  if (i >= Bc * (Hc/2)) return;
  int b = i >> 10, n = i & (Hc/2 - 1);
  o1p[(size_t)b * Sc * (Hc/2) + n] = __float2bfloat16(lf2[i]);
}

struct InvF { double v[32]; double mscale; };

__global__ void k_costab(InvF f, float* __restrict__ ct, float* __restrict__ st) {
  int i = blockIdx.x * 256 + threadIdx.x;      // MAXPOS*64
  if (i >= MAXPOS * HDc) return;
  int p = i >> 6, d = i & 63;
  double ang = (double)p * f.v[d & 31];
  ct[i] = (float)(cos(ang) * f.mscale);
  st[i] = (float)(sin(ang) * f.mscale);
}

// ---------------- RMSNorm (block per row) ----------------
__global__ __launch_bounds__(256) void k_rmsnorm(const float* __restrict__ x,
                                                 const float* __restrict__ w,
                                                 bf16* __restrict__ out) {
  __shared__ float red[4];
  int row = blockIdx.x;
  const float* xr = x + (size_t)row * Hc;
  float ss = 0.f;
  for (int c = threadIdx.x; c < Hc; c += 256) { float v = xr[c]; ss += v * v; }
  for (int off = 32; off; off >>= 1) ss += __shfl_down(ss, off, 64);
  if ((threadIdx.x & 63) == 0) red[threadIdx.x >> 6] = ss;
  __syncthreads();
  float sc = rsqrtf((red[0] + red[1] + red[2] + red[3]) / Hc + 1e-6f);
  for (int c = threadIdx.x; c < Hc; c += 256)
    out[(size_t)row * Hc + c] = __float2bfloat16(xr[c] * sc * w[c]);
}

// ---------------- 2-phase GEMM (conv1 only), default block mapping --------
template <int EPI, int BM = 128>
__global__ __launch_bounds__(256) void gemm_bt(
    const bf16* __restrict__ A0, const bf16* __restrict__ A1, int Ksplit,
    const bf16* __restrict__ Bw, int K, int N, void* __restrict__ Cout,
    const float* __restrict__ bias, const float* __restrict__ resid,
    bf16* __restrict__ aux) {
  constexpr int MR = BM / 32;
  __shared__ __align__(16) bf16 As[2][BM * 32];
  __shared__ __align__(16) bf16 Bs[2][128 * 32];
  const int tid = threadIdx.x;
  const int bm = blockIdx.y, bn = blockIdx.x;
  const int w = tid >> 6, l = tid & 63;
  const int wm = (w >> 1) * (BM / 2), wn = (w & 1) * 64;
  const int lrow = l & 15, lg = l >> 4, lk = lg * 8;
  const int r0 = tid >> 2, cofs = (tid & 3) * 8;

  auto stage = [&](int buf, int kt) {
    const int kcol = kt * 32;
    const bf16* Au; int kc;
    if (kcol < Ksplit) { Au = A0; kc = kcol; } else { Au = A1; kc = kcol - Ksplit; }
    gload16(Au + (size_t)(bm * BM + r0) * Ksplit + kc + cofs,        &As[buf][tid * 8]);
    if constexpr (BM == 128)
      gload16(Au + (size_t)(bm * BM + r0 + 64) * Ksplit + kc + cofs, &As[buf][2048 + tid * 8]);
    gload16(Bw + (size_t)(bn * 128 + r0) * K + kcol + cofs,          &Bs[buf][tid * 8]);
    gload16(Bw + (size_t)(bn * 128 + r0 + 64) * K + kcol + cofs,     &Bs[buf][2048 + tid * 8]);
  };

  f32x4 acc[MR][4] = {};
  const int nkt = K / 32;
  stage(0, 0);
  __syncthreads();
  for (int kt = 0; kt < nkt; ++kt) {
    const int cur = kt & 1;
    if (kt + 1 < nkt) stage(cur ^ 1, kt + 1);
    s16x8 af[MR], bfr[4];
#pragma unroll
    for (int m = 0; m < MR; ++m)
      af[m] = *(const s16x8*)&As[cur][(wm + m * 16 + lrow) * 32 + lk];
#pragma unroll
    for (int n = 0; n < 4; ++n)
      bfr[n] = *(const s16x8*)&Bs[cur][(wn + n * 16 + lrow) * 32 + lk];
    __builtin_amdgcn_s_setprio(1);
#pragma unroll
    for (int m = 0; m < MR; ++m)
#pragma unroll
      for (int n = 0; n < 4; ++n)
        acc[m][n] = mfma16(af[m], bfr[n], acc[m][n]);
    __builtin_amdgcn_s_setprio(0);
    __syncthreads();
  }
#pragma unroll
  for (int m = 0; m < MR; ++m)
#pragma unroll
    for (int n = 0; n < 4; ++n)
#pragma unroll
      for (int r = 0; r < 4; ++r) {
        const int grow = bm * BM + wm + m * 16 + lg * 4 + r;
        const int gcol = bn * 128 + wn + n * 16 + lrow;
        float v = acc[m][n][r];
        if constexpr (EPI == 1) {
          v += bias[gcol];
          bf16 bv = __float2bfloat16(v);
          ((bf16*)Cout)[(size_t)grow * N + gcol] = bv;
          if ((grow & (Sc - 1)) != Sc - 1) aux[(size_t)(grow + 1) * N + gcol] = bv;
        } else {
          ((float*)Cout)[(size_t)grow * N + gcol] = v;
        }
      }
}

// ---------------- 256-wide triple-buffered counted-vmcnt GEMM -------------
// EPI: 2 +bias+resid fp32 | 4 fp32 | 5 v^T store | 6 fused-RoPE q/k writer
template <int EPI, int BN>
__global__ __launch_bounds__(512, 2) void gemm8(
    const bf16* __restrict__ A0, const bf16* __restrict__ A1, int Ksplit,
    const bf16* __restrict__ Bw, int K, int N, void* __restrict__ Cout,
    const float* __restrict__ bias, const float* __restrict__ resid,
    const int* __restrict__ pos, const float* __restrict__ ct,
    const float* __restrict__ st, bf16* __restrict__ out2) {
  constexpr int BM = 256;
  constexpr int L = (BN == 256) ? 4 : 3;        // gload16 per thread per tile
  constexpr int TILE = (BM + BN) * 32;
  constexpr int MR = (BN == 256) ? 8 : 4;
  __shared__ __align__(16) bf16 lds[3][TILE];
  const int tid = threadIdx.x;
  const int w = tid >> 6, l = tid & 63;
  const int lrow = l & 15, lg = l >> 4;
  const int wm = (BN == 256) ? (w >> 2) * 128 : (w & 3) * 64;
  const int wn = (BN == 256) ? (w & 3) * 64 : (w >> 2) * 64;
  // rect XCD swizzle: XCD c gets a (gx/4)x(gy/2) block rectangle
  const int gx = gridDim.x;
  const int lin = blockIdx.y * gx + blockIdx.x;
  const int cx = gx >> 2, cy = gridDim.y >> 1;
  const int c = lin & 7, idx = lin >> 3;
  const int bn = (c & 3) * cx + idx % cx;
  const int bm = (c >> 2) * cy + idx / cx;

  auto ld1 = [&](const bf16* srcbase, size_t stride, bf16* ldst, int ci) {
    const int pr = ci >> 3, rem = ci & 7;
    const int r = pr * 2 + (rem >> 2), g = (rem & 3) ^ (pr & 3);
    gload16(srcbase + (size_t)r * stride + g * 8, ldst + ci * 8);
  };
  auto stage = [&](int kt, int slot) {
    const int kcol = kt * 32;
    const bf16* Au; int kc;
    if (kcol < Ksplit) { Au = A0; kc = kcol; } else { Au = A1; kc = kcol - Ksplit; }
    const bf16* As_ = Au + (size_t)bm * BM * Ksplit + kc;
    bf16* ldsA = lds[slot];
    ld1(As_, Ksplit, ldsA, tid);
    ld1(As_, Ksplit, ldsA, tid + 512);
    const bf16* Bs_ = Bw + (size_t)bn * BN * K + kcol;
    bf16* ldsB = lds[slot] + BM * 32;
    ld1(Bs_, K, ldsB, tid);
    if constexpr (BN == 256) ld1(Bs_, K, ldsB, tid + 512);
  };
  auto frag = [&](const bf16* base, int r) -> s16x8 {
    const int s = ((r >> 1) << 3) + ((r & 1) << 2) + (lg ^ ((r >> 1) & 3));
    return *(const s16x8*)(base + s * 8);
  };

  f32x4 acc[MR][4] = {};
  const int nkt = K / 32;
  stage(0, 0);
  stage(1, 1);
  for (int t = 0; t < nkt; ++t) {
    if (t + 2 < nkt) { stage(t + 2, (t + 2) % 3); vm_wait<2 * L>(); }
    else if (t + 1 < nkt) { vm_wait<L>(); }
    else { vm_wait<0>(); }
    block_bar();
    const bf16* Asl = lds[t % 3];
    const bf16* Bsl = Asl + BM * 32;
    s16x8 af[MR], bfr[4];
#pragma unroll
    for (int m = 0; m < MR; ++m) af[m] = frag(Asl, wm + m * 16 + lrow);
#pragma unroll
    for (int n = 0; n < 4; ++n) bfr[n] = frag(Bsl, wn + n * 16 + lrow);
    __builtin_amdgcn_s_setprio(1);
#pragma unroll
    for (int m = 0; m < MR; ++m)
#pragma unroll
      for (int n = 0; n < 4; ++n)
        acc[m][n] = mfma16(af[m], bfr[n], acc[m][n]);
    __builtin_amdgcn_s_setprio(0);
    block_bar();
  }
  if constexpr (EPI == 6) {
    // fused RoPE: wave's 64-col window = one (head, q|k) half. Pairs are
    // acc[m][n] (d) / acc[m][n+2] (d+32), n in {0,1}.
    const int gcol0 = bn * BN + wn;            // wave-uniform
    const int h = gcol0 >> 7, half = (gcol0 >> 6) & 1;
    bf16* outp = half ? out2 : (bf16*)Cout;
    const float qsc = half ? 1.0f : 0.125f * 1.44269504088896f;
#pragma unroll
    for (int m = 0; m < MR; ++m)
#pragma unroll
      for (int r = 0; r < 4; ++r) {
        const int grow = bm * BM + wm + m * 16 + lg * 4 + r;
        const int p = pos[grow];
        const int bb = grow >> 11, s = grow & (Sc - 1);
        bf16* rowp = outp + ((size_t)(bb * NHc + h) * Sc + s) * 64;
#pragma unroll
        for (int n = 0; n < 2; ++n) {
          const int dd = n * 16 + lrow;
          const float c0 = ct[p * 64 + dd],      s0 = st[p * 64 + dd];
          const float c1 = ct[p * 64 + 32 + dd], s1 = st[p * 64 + 32 + dd];
          const float v0 = acc[m][n][r], v1 = acc[m][n + 2][r];
          rowp[dd]      = __float2bfloat16((v0 * c0 - v1 * s0) * qsc);
          rowp[dd + 32] = __float2bfloat16((v1 * c1 + v0 * s1) * qsc);
        }
      }
  } else {
#pragma unroll
    for (int m = 0; m < MR; ++m)
#pragma unroll
      for (int n = 0; n < 4; ++n)
#pragma unroll
        for (int r = 0; r < 4; ++r) {
          const int grow = bm * BM + wm + m * 16 + lg * 4 + r;
          const int gcol = bn * BN + wn + n * 16 + lrow;
          float v = acc[m][n][r];
          if constexpr (EPI == 2) {
            v += bias[gcol] + resid[(size_t)grow * N + gcol];
            ((float*)Cout)[(size_t)grow * N + gcol] = v;
          } else if constexpr (EPI == 5) {
            const int b = gcol >> 11, s = gcol & (Sc - 1);
            ((bf16*)Cout)[((size_t)(b * Hc + grow)) * Sc + s] = __float2bfloat16(v);
          } else {
            ((float*)Cout)[(size_t)grow * N + gcol] = v;
          }
        }
  }
}

// ---------------- causal flash attention (block-staged K/V, KVBLK=64) -----
// Round-10 proven version: 2-slot double buffer, __syncthreads protocol,
// 53KB LDS -> 3 blocks/CU (occupancy is the binding constraint; the 3-slot
// counted-vmcnt variant cost a block/CU and regressed 87->129us).
__global__ __launch_bounds__(256) void k_attn(const bf16* __restrict__ Q,
                                              const bf16* __restrict__ Kg,
                                              const bf16* __restrict__ Vt,
                                              bf16* __restrict__ ctx) {
  __shared__ __align__(16) bf16 Ks[2][64 * 64];
  __shared__ __align__(16) bf16 Vs[2][64 * 64];
  __shared__ __align__(16) uint32_t Pl[4][2][2][16][20];
  const int tid = threadIdx.x;
  const int w = tid >> 6, l = tid & 63;
  const int lrow = l & 15, lg = l >> 4, lk = lg * 8;
  const int bh = blockIdx.x;
  const int tile = blockIdx.y;
  const bf16* Qp = Q  + (size_t)bh * Sc * HDc;
  const bf16* Kp = Kg + (size_t)bh * Sc * HDc;
  const bf16* Vp = Vt + (size_t)bh * HDc * Sc;
  const int b = bh >> 5, h = bh & 31;
  const s16x8 ones8 = {16256, 16256, 16256, 16256, 16256, 16256, 16256, 16256};

  const int srow0 = tid >> 3, schunk = tid & 7;

  for (int pass = 0; pass < 2; ++pass) {
    const int base = (pass == 0) ? tile * 128 : (Sc - 128 - tile * 128);
    const int q0 = base + w * 32;
    const int NT = base / 64 + 2;

    s16x8 qa[2][2];
#pragma unroll
    for (int m = 0; m < 2; ++m)
#pragma unroll
      for (int hf = 0; hf < 2; ++hf)
        qa[m][hf] = *(const s16x8*)&Qp[(size_t)(q0 + m * 16 + lrow) * 64 + hf * 32 + lk];

    f32x4 o[2][4] = {};
    f32x4 lsf[2] = {};
    float mx[2] = {-1e30f, -1e30f};

    {
      gload16(Kp + (size_t)srow0 * 64 + ((schunk ^ (srow0 & 7)) << 3), &Ks[0][tid * 8]);
      gload16(Kp + (size_t)(32 + srow0) * 64 + ((schunk ^ ((32 + srow0) & 7)) << 3),
              &Ks[0][2048 + tid * 8]);
      gload16(Vp + (size_t)srow0 * Sc + ((schunk ^ (srow0 & 7)) << 3), &Vs[0][tid * 8]);
      gload16(Vp + (size_t)(32 + srow0) * Sc + ((schunk ^ ((32 + srow0) & 7)) << 3),
              &Vs[0][2048 + tid * 8]);
    }
    __syncthreads();

    for (int t = 0; t < NT; ++t) {
      const int cur = t & 1;
      const int kv0 = t * 64;
      if (t + 1 < NT) {
        const int nkv = kv0 + 64;
        const int nb = cur ^ 1;
        gload16(Kp + (size_t)(nkv + srow0) * 64 + ((schunk ^ (srow0 & 7)) << 3),
                &Ks[nb][tid * 8]);
        gload16(Kp + (size_t)(nkv + 32 + srow0) * 64 + ((schunk ^ ((32 + srow0) & 7)) << 3),
                &Ks[nb][2048 + tid * 8]);
        gload16(Vp + (size_t)srow0 * Sc + nkv + ((schunk ^ (srow0 & 7)) << 3),
                &Vs[nb][tid * 8]);
        gload16(Vp + (size_t)(32 + srow0) * Sc + nkv + ((schunk ^ ((32 + srow0) & 7)) << 3),
                &Vs[nb][2048 + tid * 8]);
      }
      if (kv0 <= q0) {
        s16x8 kc[8], vc[4][2];
#pragma unroll
        for (int c = 0; c < 4; ++c)
#pragma unroll
          for (int hf = 0; hf < 2; ++hf) {
            const int row = c * 16 + lrow;
            kc[c * 2 + hf] =
                *(const s16x8*)&Ks[cur][row * 64 + (((hf << 2) + lg) ^ (row & 7)) * 8];
          }
#pragma unroll
        for (int db = 0; db < 4; ++db)
#pragma unroll
          for (int kh = 0; kh < 2; ++kh) {
            const int row = db * 16 + lrow;
            vc[db][kh] =
                *(const s16x8*)&Vs[cur][row * 64 + (((kh << 2) + lg) ^ (row & 7)) * 8];
          }
        const bool lastit = (kv0 + 64 > q0);

#pragma unroll
        for (int m = 0; m < 2; ++m) {
          f32x4 s[4];
          __builtin_amdgcn_s_setprio(1);
#pragma unroll
          for (int c = 0; c < 4; ++c) {
            f32x4 z = {};
            z = mfma16(kc[c * 2], qa[m][0], z);
            z = mfma16(kc[c * 2 + 1], qa[m][1], z);
            s[c] = z;
          }
          __builtin_amdgcn_s_setprio(0);

          if (lastit) {
            const int qq = q0 + m * 16 + lrow;
#pragma unroll
            for (int c = 0; c < 4; ++c)
#pragma unroll
              for (int r = 0; r < 4; ++r)
                if (kv0 + c * 16 + lg * 4 + r > qq) s[c][r] = -1e30f;
          }
          float t16 = fmaxf(
              fmaxf(fmaxf(fmaxf(s[0][0], s[0][1]), fmaxf(s[0][2], s[0][3])),
                    fmaxf(fmaxf(s[1][0], s[1][1]), fmaxf(s[1][2], s[1][3]))),
              fmaxf(fmaxf(fmaxf(s[2][0], s[2][1]), fmaxf(s[2][2], s[2][3])),
                    fmaxf(fmaxf(s[3][0], s[3][1]), fmaxf(s[3][2], s[3][3]))));
          if (!__all(t16 <= mx[m] + 8.0f)) {
            t16 = fmaxf(t16, __shfl_xor(t16, 16, 64));
            t16 = fmaxf(t16, __shfl_xor(t16, 32, 64));
            const float mnew = fmaxf(mx[m], t16);
            const float sold = __builtin_amdgcn_exp2f(mx[m] - mnew);
            mx[m] = mnew;
            lsf[m] *= sold;
#pragma unroll
            for (int db = 0; db < 4; ++db) o[m][db] *= sold;
          }
          float p[4][4];
#pragma unroll
          for (int c = 0; c < 4; ++c)
#pragma unroll
            for (int r = 0; r < 4; ++r)
              p[c][r] = __builtin_amdgcn_exp2f(s[c][r] - mx[m]);
#pragma unroll
          for (int kh = 0; kh < 2; ++kh) {
            *(uint64_t*)&Pl[w][m][kh][lrow][lg * 2] =
                (uint64_t)pkbf(p[kh * 2][0], p[kh * 2][1]) |
                ((uint64_t)pkbf(p[kh * 2][2], p[kh * 2][3]) << 32);
            *(uint64_t*)&Pl[w][m][kh][lrow][8 + lg * 2] =
                (uint64_t)pkbf(p[kh * 2 + 1][0], p[kh * 2 + 1][1]) |
                ((uint64_t)pkbf(p[kh * 2 + 1][2], p[kh * 2 + 1][3]) << 32);
          }
          const s16x8 pb0 = *(const s16x8*)&Pl[w][m][0][lrow][lg * 4];
          const s16x8 pb1 = *(const s16x8*)&Pl[w][m][1][lrow][lg * 4];
          __builtin_amdgcn_s_setprio(1);
#pragma unroll
          for (int db = 0; db < 4; ++db) o[m][db] = mfma16(vc[db][0], pb0, o[m][db]);
          lsf[m] = mfma16(ones8, pb0, lsf[m]);
#pragma unroll
          for (int db = 0; db < 4; ++db) o[m][db] = mfma16(vc[db][1], pb1, o[m][db]);
          lsf[m] = mfma16(ones8, pb1, lsf[m]);
          __builtin_amdgcn_s_setprio(0);
        }
      }
      __syncthreads();
    }
#pragma unroll
    for (int m = 0; m < 2; ++m) {
      const float inv = 1.0f / lsf[m][0];
      const int qrow = q0 + m * 16 + lrow;
      const size_t rowoff = ((size_t)(b * Sc + qrow)) * Hc + h * 64;
#pragma unroll
      for (int db = 0; db < 4; ++db) {
        uint64_t pk = (uint64_t)bfbits(o[m][db][0] * inv) |
                      ((uint64_t)bfbits(o[m][db][1] * inv) << 16) |
                      ((uint64_t)bfbits(o[m][db][2] * inv) << 32) |
                      ((uint64_t)bfbits(o[m][db][3] * inv) << 48);
        *(uint64_t*)&ctx[rowoff + db * 16 + lg * 4] = pk;
      }
    }
    __syncthreads();
  }
}

// ---------------- host ----------------
extern "C" void kernel_launch(void* const* d_in, const int* in_sizes, int n_in,
                              void* d_out, int out_size, void* d_ws, size_t ws_size,
                              hipStream_t stream) {
  (void)in_sizes; (void)n_in; (void)out_size; (void)ws_size;
  const float* hs  = (const float*)d_in[0];
  const int*   pos = (const int*)d_in[1];
  const float* lf1 = (const float*)d_in[2];
  const float* lf2 = (const float*)d_in[3];
  const float* Wqk = (const float*)d_in[4];
  const float* Wv  = (const float*)d_in[5];
  const float* Wo  = (const float*)d_in[6];
  const float* c1w = (const float*)d_in[7];
  const float* c1b = (const float*)d_in[8];
  const float* c2w = (const float*)d_in[9];
  const float* c2b = (const float*)d_in[10];
  const float* lnw = (const float*)d_in[11];
  float* out = (float*)d_out;
  char*  ws  = (char*)d_ws;

  bf16* wvB   = (bf16*)(ws + OFF_WV);
  bf16* wqkB  = (bf16*)(ws + OFF_WQK);
  bf16* woB   = (bf16*)(ws + OFF_WO);
  bf16* w1B   = (bf16*)(ws + OFF_W1);
  bf16* w2B   = (bf16*)(ws + OFF_W2);
  bf16* hsB   = (bf16*)(ws + OFF_HS);
  bf16* xprB  = (bf16*)(ws + OFF_XPR);
  bf16* o1B   = (bf16*)(ws + OFF_O1);
  bf16* o1pB  = (bf16*)(ws + OFF_O1P);
  float* o2F  = (float*)(ws + OFF_O2);
  bf16* lfB   = (bf16*)(ws + OFF_LF);
  bf16* vtB   = (bf16*)(ws + OFF_VT);
  float* cosT = (float*)(ws + OFF_COS);
  float* sinT = (float*)(ws + OFF_SIN);
  bf16* qB    = (bf16*)(ws + OFF_Q);
  bf16* kB    = (bf16*)(ws + OFF_K);
  bf16* ctxB  = (bf16*)(ws + OFF_CTX);

  // YaRN inv_freq on host (fp64), matching the reference exactly
  InvF f;
  {
    const double base = 10000.0, scale = 2.0;
    const int hd = HDc;
    auto corr = [&](double nr) {
      return hd * log(8192.0 / (nr * 2.0 * M_PI)) / (2.0 * log(base));
    };
    double low = floor(corr(32.0)); if (low < 0) low = 0;
    double high = ceil(corr(1.0));  if (high > hd - 1) high = hd - 1;
    double hi = (low == high) ? high + 0.001 : high;
    for (int i = 0; i < 32; ++i) {
      double inv = 1.0 / pow(base, (2.0 * i) / hd);
      double ramp = ((double)i - low) / (hi - low);
      ramp = ramp < 0.0 ? 0.0 : (ramp > 1.0 ? 1.0 : ramp);
      double mask = 1.0 - ramp;
      f.v[i] = inv / ((1.0 - mask) * scale + mask);
    }
    f.mscale = 0.1 * log(scale) + 1.0;
  }

  // conversions / repacks / tables
  k_cvt<<<(Hc * Hc + 255) / 256, 256, 0, stream>>>(Wv, wvB, Hc * Hc);
  k_cvt<<<(2 * Hc * Hc + 255) / 256, 256, 0, stream>>>(Wqk, wqkB, 2 * Hc * Hc);
  k_cvt<<<(Hc * Hc + 255) / 256, 256, 0, stream>>>(Wo, woB, Hc * Hc);
  k_repack1<<<((Hc / 2) * 2 * Hc + 255) / 256, 256, 0, stream>>>(c1w, w1B);
  k_repack2<<<(Hc * Hc + 255) / 256, 256, 0, stream>>>(c2w, w2B);
  k_cvt_hs<<<(Mc * Hc + 255) / 256, 256, 0, stream>>>(hs, lf1, hsB, xprB);
  k_prefill_o1p<<<(Bc * (Hc / 2) + 255) / 256, 256, 0, stream>>>(lf2, o1pB);
  k_costab<<<(MAXPOS * HDc + 255) / 256, 256, 0, stream>>>(f, cosT, sinT);

  // conv1: o1 = [xprev|x] @ w1cat^T + b1  (2-phase, BM=64)
  gemm_bt<1, 64><<<dim3((Hc / 2) / 128, Mc / 64), 256, 0, stream>>>(
      xprB, hsB, Hc, w1B, 2 * Hc, Hc / 2, o1B, c1b, nullptr, o1pB);
  // v^T: C'[hd][(b,s)] = Wv @ hs^T
  gemm8<5, 128><<<dim3(Mc / 128, Hc / 256), 512, 0, stream>>>(
      wvB, wvB, Hc, hsB, Hc, Mc, vtB, nullptr, nullptr, nullptr, nullptr, nullptr, nullptr);
  // conv2: o2res = [o1prev|o1] @ w2cat^T + b2 + hidden  (fp32)
  gemm8<2, 128><<<dim3(Hc / 128, Mc / 256), 512, 0, stream>>>(
      o1pB, o1B, Hc / 2, w2B, Hc, Hc, o2F, c2b, hs, nullptr, nullptr, nullptr, nullptr);
  // lf = rmsnorm(o2res) * ln_w
  k_rmsnorm<<<Mc, 256, 0, stream>>>(o2F, lnw, lfB);
  // qk = lf @ Wqk^T with fused RoPE -> q (pre-scaled, exp2 domain), k
  gemm8<6, 256><<<dim3((2 * Hc) / 256, Mc / 256), 512, 0, stream>>>(
      lfB, lfB, Hc, wqkB, Hc, 2 * Hc, qB, nullptr, nullptr, pos, cosT, sinT, kB);
  // causal flash attention -> ctx (b,s,h*64+d)
  k_attn<<<dim3(64, 8), 256, 0, stream>>>(qB, kB, vtB, ctxB);
  // out = ctx @ Wo^T  (fp32)
  gemm8<4, 128><<<dim3(Hc / 128, Mc / 256), 512, 0, stream>>>(
      ctxB, ctxB, Hc, woB, Hc, Hc, out, nullptr, nullptr, nullptr, nullptr, nullptr, nullptr);
}